// Round 5
// baseline (253.289 us; speedup 1.0000x reference)
//
#include <hip/hip_runtime.h>
#include <math.h>

#define BB   16
#define NNODE 1024
#define INF_ 128
#define HH   32
#define KMC  16
#define CAP  128
#define EPS15 1e-15f

typedef float v4f __attribute__((ext_vector_type(4)));

// ---- workspace layout (float offsets) ----
#define OFF_X      0           // [B*N*32]
#define OFF_SRW    524288      // float2 [B*N]
#define OFF_SQCT   557056      // [B*N]
#define OFF_SCT    573440      // [B*N*32]
#define OFF_D      1097728     // [B*N]
#define OFF_NUMRW  1114112
#define OFF_SAS    1130496
#define OFF_DGAP   1146880
#define OFF_DCT    1163264
#define OFF_XGAP   2228224     // [B*N*32]
#define OFF_XCT    2752512     // [B*N*32]
#define OFF_S2G    3276800     // [B*N*16]
#define OFF_S2C    3538944
#define OFF_FROB   4325376     // [B*32]
#define OFF_VOL    4325888     // [16]
#define OFF_OUTG   4326032     // [B*16*32]
#define OFF_OUTC   4334224
#define OFF_G2G    4342416     // [B*16*16]
#define OFF_G2C    4346512
#define OFF_OAG    4350608
#define OFF_OAC    4354704
// ---- edge cache ----
#define OFF_ENNZ   4358800     // int[16384]
#define OFF_EIDX   4375184     // u16[16384*CAP] = 1048576 floats
#define OFF_EWG    5423760     // float[16384*CAP]
#define OFF_EWC    7520912     // float[16384*CAP]
#define OFF_PACK   9618064     // float4 [B*N] : (srw.x, srw.y, sqct, 0)
#define OFF_BSUM   9683600     // [B*12] per-batch loss partials (atomic, from k_passred)

__device__ __forceinline__ float wave_sum(float v) {
#pragma unroll
  for (int off = 32; off >= 1; off >>= 1) v += __shfl_xor(v, off, 64);
  return v;
}

__device__ __forceinline__ void wave_sum4(float& a, float& b, float& c, float& d) {
#pragma unroll
  for (int off = 32; off >= 1; off >>= 1) {
    a += __shfl_xor(a, off, 64);
    b += __shfl_xor(b, off, 64);
    c += __shfl_xor(c, off, 64);
    d += __shfl_xor(d, off, 64);
  }
}

// reduce float4 across the 16 4-lane teams of a wave (lanes equal mod 4 sum up)
__device__ __forceinline__ void team_reduce_f4(float4& a) {
#pragma unroll
  for (int off = 4; off <= 32; off <<= 1) {
    a.x += __shfl_xor(a.x, off, 64);
    a.y += __shfl_xor(a.y, off, 64);
    a.z += __shfl_xor(a.z, off, 64);
    a.w += __shfl_xor(a.w, off, 64);
  }
}

__device__ __forceinline__ float blk_sum(float v, float* sred, int tid) {
  v = wave_sum(v);
  __syncthreads();
  if ((tid & 63) == 0) sred[tid >> 6] = v;
  __syncthreads();
  return sred[0] + sred[1] + sred[2] + sred[3];
}

// 5 simultaneous block reductions (2 syncthreads total)
__device__ __forceinline__ void blk_sum5(float* v, float (*sm)[4], int tid) {
  int w = tid >> 6, lane = tid & 63;
#pragma unroll
  for (int i = 0; i < 5; i++) {
#pragma unroll
    for (int off = 32; off >= 1; off >>= 1) v[i] += __shfl_xor(v[i], off, 64);
  }
  if (lane == 0) {
#pragma unroll
    for (int i = 0; i < 5; i++) sm[i][w] = v[i];
  }
  __syncthreads();
#pragma unroll
  for (int i = 0; i < 5; i++) v[i] = sm[i][0] + sm[i][1] + sm[i][2] + sm[i][3];
}

// ============ K1: blocks [0,1024) = adj scan->edge list (4 rows/wave) ;
//              [1024,3072) = prep (X=x@W1+b1, sct/srw softmaxes) ============
__global__ __launch_bounds__(256) void k_fused0(
    const float* __restrict__ adj, const float* __restrict__ x,
    const float* __restrict__ W1, const float* __restrict__ b1,
    const float* __restrict__ Wrw, const float* __restrict__ brw,
    const float* __restrict__ Wct, const float* __restrict__ bct,
    float* __restrict__ ws)
{
  __shared__ __align__(16) float sW1[INF_*HH];
  __shared__ __align__(16) float sWct[HH*HH];
  __shared__ float sWrw[HH*2];
  __shared__ float sb1[HH], sbct[HH], sbrw[2];
  __shared__ __align__(16) float sx[8*INF_];
  __shared__ float sX[8*HH];
  __shared__ unsigned int s_e32[4][4][CAP/2];
  int tid = threadIdx.x;
  if (blockIdx.x < 1024) {
    // -------- scan role: 4 rows per wave, 16 NT loads in flight --------
    int w = tid >> 6, lane = tid & 63;
    int row0 = blockIdx.x * 16 + w * 4;
    v4f v[16];
#pragma unroll
    for (int rr = 0; rr < 4; rr++) {
      const v4f* ar = (const v4f*)(adj + (size_t)(row0 + rr) * NNODE);
#pragma unroll
      for (int it = 0; it < 4; it++)
        v[rr*4 + it] = __builtin_nontemporal_load(&ar[it*64 + lane]);
    }
#pragma unroll
    for (int rr = 0; rr < 4; rr++) {
      int row = row0 + rr;
      int c = 0;
#pragma unroll
      for (int it = 0; it < 4; it++) {
        v4f a4 = v[rr*4 + it];
        c += (a4.x != 0.f) + (a4.y != 0.f) + (a4.z != 0.f) + (a4.w != 0.f);
      }
      int p = c;
#pragma unroll
      for (int off = 1; off < 64; off <<= 1) {
        int t = __shfl_up(p, off, 64);
        if (lane >= off) p += t;
      }
      int excl = p - c;
      int total = __shfl(p, 63, 64);
      unsigned short* es = (unsigned short*)s_e32[w][rr];
      int pos = excl;
#pragma unroll
      for (int it = 0; it < 4; it++) {
        v4f a4 = v[rr*4 + it];
        int m0 = it*256 + lane*4;
        if (a4.x != 0.f) { if (pos < CAP) es[pos] = (unsigned short)(m0+0); pos++; }
        if (a4.y != 0.f) { if (pos < CAP) es[pos] = (unsigned short)(m0+1); pos++; }
        if (a4.z != 0.f) { if (pos < CAP) es[pos] = (unsigned short)(m0+2); pos++; }
        if (a4.w != 0.f) { if (pos < CAP) es[pos] = (unsigned short)(m0+3); pos++; }
      }
      int nnzc = total < CAP ? total : CAP;
      __syncthreads();
      unsigned int* dst = (unsigned int*)((unsigned short*)(ws + OFF_EIDX) + (size_t)row*CAP);
      int n32 = (nnzc + 1) >> 1;
      if (lane < n32) dst[lane] = s_e32[w][rr][lane];
      if (lane == 0) {
        ((int*)(ws + OFF_ENNZ))[row] = nnzc;
        ws[OFF_D + row] = (float)total;
      }
    }
  } else {
    // -------- prep role --------
    for (int i = tid; i < INF_*HH/4; i += 256)
      ((float4*)sW1)[i] = ((const float4*)W1)[i];
    ((float4*)sWct)[tid] = ((const float4*)Wct)[tid];
    if (tid < HH*2) sWrw[tid] = Wrw[tid];
    if (tid < HH) { sb1[tid] = b1[tid]; sbct[tid] = bct[tid]; }
    if (tid < 2) sbrw[tid] = brw[tid];
    size_t row0 = (size_t)(blockIdx.x - 1024) * 8;
    ((float4*)sx)[tid] = ((const float4*)(x + row0 * INF_))[tid];
    __syncthreads();
    int r = tid >> 5, h = tid & 31;
    float acc = sb1[h];
#pragma unroll 8
    for (int k = 0; k < INF_; k++) acc += sx[r*INF_ + k] * sW1[k*HH + h];
    size_t row = row0 + r;
    ws[OFF_X + row*HH + h] = acc;
    sX[r*HH + h] = acc;
    __syncthreads();
    // sct softmax over 32
    float sraw = sbct[h];
#pragma unroll
    for (int k = 0; k < HH; k++) sraw += sX[r*HH + k] * sWct[k*HH + h];
    float mx = sraw;
#pragma unroll
    for (int off = 16; off >= 1; off >>= 1) mx = fmaxf(mx, __shfl_xor(mx, off, 32));
    float e = __expf(sraw - mx);
    float sum = e;
#pragma unroll
    for (int off = 16; off >= 1; off >>= 1) sum += __shfl_xor(sum, off, 32);
    float sv = e / sum;
    ws[OFF_SCT + row*HH + h] = sv;
    float sq = sv * sv;
#pragma unroll
    for (int off = 16; off >= 1; off >>= 1) sq += __shfl_xor(sq, off, 32);
    // srw (k=2)
    float xv = sX[r*HH + h];
    float t0 = xv * sWrw[h*2 + 0];
    float t1 = xv * sWrw[h*2 + 1];
#pragma unroll
    for (int off = 16; off >= 1; off >>= 1) { t0 += __shfl_xor(t0, off, 32); t1 += __shfl_xor(t1, off, 32); }
    if (h == 0) {
      ws[OFF_SQCT + row] = sq;
      float r0 = t0 + sbrw[0], r1 = t1 + sbrw[1];
      float m2 = fmaxf(r0, r1);
      float e0 = __expf(r0 - m2), e1 = __expf(r1 - m2);
      float inv = 1.0f / (e0 + e1);
      float s0 = e0*inv, s1 = e1*inv;
      ((float2*)(ws + OFF_SRW))[row] = make_float2(s0, s1);
      ((float4*)(ws + OFF_PACK))[row] = make_float4(s0, s1, sq, 0.f);
    }
  }
}

// ============ K2: [0,1024) WAVE-INDEPENDENT edge role — zero barriers.
//              Each wave: 4 rows sequentially {fused edge pass -> stats ->
//              y team-reduce -> DGC (weights from L2) -> S2 softmax}, all
//              intermediates in wave-private LDS. 16 rows/block.
//              [1024,1536) gramfrob ; [1536,1552) VOL + zero accums ============
__global__ __launch_bounds__(256) void k_edgefeat(
    const float* __restrict__ Wg_rel, const float* __restrict__ bg, const float* __restrict__ Wg_root,
    const float* __restrict__ Wc_rel, const float* __restrict__ bc, const float* __restrict__ Wc_root,
    const float* __restrict__ Wmcg, const float* __restrict__ bmcg,
    const float* __restrict__ Wmcc, const float* __restrict__ bmcc,
    float* __restrict__ out, float* __restrict__ ws)
{
  __shared__ float sp[8][32];
  __shared__ float sred[4];
  __shared__ __align__(16) float sY[4][2][HH];   // [wave][G/C][h] (wave-private)
  __shared__ __align__(16) float sXw[4][HH];     // own-row X      (wave-private)
  __shared__ float sxgw[4][HH], sxcw[4][HH];     // DGC outputs    (wave-private)
  int tid = threadIdx.x;
  if (blockIdx.x < 1024) {
    // XCD swizzle: xcd = blk&7 handles batches {2*xcd, 2*xcd+1}
    int xcd = blockIdx.x & 7;
    int idx = blockIdx.x >> 3;              // 0..127
    int b = xcd*2 + (idx >> 6);             // batch
    int chunk = idx & 63;                   // 16-row chunk
    int base16 = b*NNODE + chunk*16;
    int w = tid >> 6, lane = tid & 63;
    int tm = lane & 3;                      // 4-lane team member (h-slice tm*8..+8)
    int h = lane & 31, half = lane >> 5;    // DGC mapping
    int j = lane & 15, gsel = (lane >> 4) & 1;  // S2 mapping
    const float* X = ws + OFF_X;
    const float* sct = ws + OFF_SCT;
    const float2* srw = (const float2*)(ws + OFF_SRW);
    const float* sqct = ws + OFF_SQCT;
    const float4* pack = (const float4*)(ws + OFF_PACK) + (size_t)b*NNODE;
    // hoisted biases (L2-hot)
    float bgv = bg[h], bcv = bc[h];
    float bmv = gsel ? bmcc[j] : bmcg[j];
    const float* Wmc = gsel ? Wmcc : Wmcg;
    // wave-local VOL (16 coalesced L2 loads + wave reduce; no barrier)
    float vp = 0.f;
#pragma unroll
    for (int i = 0; i < 16; i++) vp += ws[OFF_D + (size_t)b*NNODE + lane + i*64];
    float ivol = 1.0f / (wave_sum(vp) + EPS15);

    for (int rr = 0; rr < 4; rr++) {
      int row = base16 + w*4 + rr;
      int nnz = ((const int*)(ws + OFF_ENNZ))[row];
      const unsigned short* eidx = (const unsigned short*)(ws + OFF_EIDX) + (size_t)row*CAP;
      // own-row sct fragment: 8 floats per lane (team covers all 32)
      const float4* cn4 = (const float4*)(sct + (size_t)row * HH);
      float4 c0 = cn4[tm*2], c1 = cn4[tm*2 + 1];
      // stage own-row X into wave-private LDS (read later by DGC)
      if (lane < 8) ((float4*)sXw[w])[lane] = ((const float4*)(X + (size_t)row * HH))[lane];
      float2 srwn = srw[row];
      float f_n = srwn.x;
      float sq_n = sqct[row];
      float numrw_p = 0.f, sas_p = 0.f, dg_p = 0.f, dc_p = 0.f;
      float4 yg0 = make_float4(0,0,0,0), yg1 = make_float4(0,0,0,0);
      float4 yc0 = make_float4(0,0,0,0), yc1 = make_float4(0,0,0,0);
      // FUSED edge pass: one edge per 4-lane team; gathers sct-slice, X-slice, pack
      for (int e = (lane >> 2); e < nnz; e += 16) {
        int m = eidx[e];
        size_t mo = ((size_t)b*NNODE + m);
        const float4* cm4 = (const float4*)(sct + mo * HH);
        const float4* xm4 = (const float4*)(X + mo * HH);
        float4 d0 = cm4[tm*2], d1 = cm4[tm*2 + 1];
        float4 x0 = xm4[tm*2], x1 = xm4[tm*2 + 1];
        float4 pk = pack[m];                  // (srw.x, srw.y, sqct)
        float dot = c0.x*d0.x + c0.y*d0.y + c0.z*d0.z + c0.w*d0.w
                  + c1.x*d1.x + c1.y*d1.y + c1.z*d1.z + c1.w*d1.w;
        dot += __shfl_xor(dot, 1, 64);
        dot += __shfl_xor(dot, 2, 64);        // all 4 team lanes hold full dot
        numrw_p += srwn.x*pk.x + srwn.y*pk.y;
        float df = f_n - pk.x;
        float wg = 1.0f - df*df;
        float d2 = sq_n + pk.z - 2.0f*dot;
        float wc = sqrtf(fmaxf(d2, 0.0f) + 1e-12f);
        sas_p += dot;
        dg_p += wg;
        dc_p += wc;
        yg0.x += wg*x0.x; yg0.y += wg*x0.y; yg0.z += wg*x0.z; yg0.w += wg*x0.w;
        yg1.x += wg*x1.x; yg1.y += wg*x1.y; yg1.z += wg*x1.z; yg1.w += wg*x1.w;
        yc0.x += wc*x0.x; yc0.y += wc*x0.y; yc0.z += wc*x0.z; yc0.w += wc*x0.w;
        yc1.x += wc*x1.x; yc1.y += wc*x1.y; yc1.z += wc*x1.z; yc1.w += wc*x1.w;
        if (tm == 0) {
          size_t eo = (size_t)row*CAP + e;
          ws[OFF_EWG + eo] = wg;
          ws[OFF_EWC + eo] = wc;
        }
      }
      wave_sum4(numrw_p, sas_p, dg_p, dc_p);  // 4x duplicated across team -> scale
      if (lane == 0) {
        ws[OFF_NUMRW + row] = numrw_p * 0.25f;
        ws[OFF_SAS + row] = sas_p * 0.25f;
        ws[OFF_DGAP + row] = dg_p * 0.25f;
        ws[OFF_DCT + row] = dc_p * 0.25f;
      }
      // y: reduce across the 16 teams; lanes 0..3 hold h-slices tm*8..+8
      team_reduce_f4(yg0); team_reduce_f4(yg1);
      team_reduce_f4(yc0); team_reduce_f4(yc1);
      if (lane < 4) {
        ((float4*)&sY[w][0][tm*8])[0] = yg0;
        ((float4*)&sY[w][0][tm*8])[1] = yg1;
        ((float4*)&sY[w][1][tm*8])[0] = yc0;
        ((float4*)&sY[w][1][tm*8])[1] = yc1;
      }
      // ---- DGC: k-split x2 across half; weights straight from L2 ----
      {
        float accg = 0.f, accg2 = 0.f, accc = 0.f, accc2 = 0.f;
#pragma unroll
        for (int kk = 0; kk < 16; kk++) {
          int k = half*16 + kk;
          float ygv = sY[w][0][k], Xv = sXw[w][k], ycv = sY[w][1][k];
          accg  += ygv * Wg_rel[k*HH + h];
          accg2 += Xv  * Wg_root[k*HH + h];
          accc  += ycv * Wc_rel[k*HH + h];
          accc2 += Xv  * Wc_root[k*HH + h];
        }
        accg  += __shfl_xor(accg, 32, 64);
        accg2 += __shfl_xor(accg2, 32, 64);
        accc  += __shfl_xor(accc, 32, 64);
        accc2 += __shfl_xor(accc2, 32, 64);
        float xgv = bgv + accg + accg2;
        float xcv = bcv + ivol*accc + accc2;
        if (half == 0) {
          ws[OFF_XGAP + (size_t)row*HH + h] = xgv;
          ws[OFF_XCT  + (size_t)row*HH + h] = xcv;
          sxgw[w][h] = xgv;
          sxcw[w][h] = xcv;
        }
      }
      // ---- S2 softmax, wave-local: (half, gsel, j); k-split + 16-lane shuffles ----
      {
        const float* xin = gsel ? sxcw[w] : sxgw[w];
        float raw = 0.f;
#pragma unroll
        for (int kk = 0; kk < 16; kk++) {
          int k = half*16 + kk;
          raw += xin[k] * Wmc[k*KMC + j];
        }
        raw += __shfl_xor(raw, 32, 64);       // combine k-halves (both halves hold sum)
        raw += bmv;
        float mx = raw;
#pragma unroll
        for (int off = 8; off >= 1; off >>= 1) mx = fmaxf(mx, __shfl_xor(mx, off, 64));
        float e = __expf(raw - mx);
        float sum = e;
#pragma unroll
        for (int off = 8; off >= 1; off >>= 1) sum += __shfl_xor(sum, off, 64);
        float sv = e / sum;
        if (half == 0) {
          if (gsel == 0) ws[OFF_S2G + (size_t)row*KMC + j] = sv;
          else           ws[OFF_S2C + (size_t)row*KMC + j] = sv;
        }
      }
    }
  } else if (blockIdx.x < 1536) {
    // -------- gramfrob role (XCD-affine) --------
    int blk = blockIdx.x - 1024;     // 0..511
    int xcd = blk & 7;
    int idx = blk >> 3;              // 0..63
    int b = xcd*2 + (idx >> 5);
    int i = idx & 31;
    const float* sct = ws + OFF_SCT + (size_t)b*NNODE*HH;
    int j = tid & 31, seg = tid >> 5;
    float acc = 0.f;
    for (int n = seg*128; n < seg*128 + 128; n++)
      acc += sct[n*HH + i] * sct[n*HH + j];
    sp[seg][j] = acc;
    __syncthreads();
    if (tid < 32) {
      float g = 0.f;
#pragma unroll
      for (int s = 0; s < 8; s++) g += sp[s][tid];
      float p = g * g;
#pragma unroll
      for (int off = 16; off >= 1; off >>= 1) p += __shfl_xor(p, off, 32);
      if (tid == 0) ws[OFF_FROB + b*32 + i] = p;
    }
  } else {
    // -------- batch-prep role: VOL[b] ; zero K3 accumulators + BSUM + loss outs --------
    int b = blockIdx.x - 1536;       // 0..15
    if (b == 0 && tid < 2) out[160 + tid] = 0.f;
    if (tid < 12) ws[OFF_BSUM + b*12 + tid] = 0.f;
    for (int i = tid; i < 2048; i += 256) ws[OFF_OUTG + b*2048 + i] = 0.f;
    float vp = 0.f;
    for (int n = tid; n < NNODE; n += 256) vp += ws[OFF_D + (size_t)b*NNODE + n];
    float vol = blk_sum(vp, sred, tid);
    if (tid == 0) ws[OFF_VOL + b] = vol;
  }
}

// ============ K3: fused edge-SpMM + red2 + BSUM. XCD-affine (S2/X/EW L2-local).
//              512 blocks x 512 threads; one (row,k) pair per thread: 16 k-lanes
//              of a row read CONTIGUOUS S2 bytes (coalesced), G+C in-thread,
//              2-edge unroll -> 4 gathers in flight, no shuffles. ============
__global__ __launch_bounds__(512) void k_passred(float* __restrict__ ws)
{
  __shared__ float sg[32*16], sc[32*16], stg[32*16], stc[32*16];
  __shared__ float sxg[32*32], sxc[32*32];
  // XCD swizzle mirrors k_edgefeat: xcd = blk&7 -> batches {2*xcd, 2*xcd+1}
  int xcd = blockIdx.x & 7;
  int idx = blockIdx.x >> 3;       // 0..63
  int b = xcd*2 + (idx >> 5);
  int chunk = idx & 31;
  int tid = threadIdx.x;
  size_t n0 = (size_t)b * NNODE + chunk * 32;
  const float* pG  = ws + OFF_S2G  + n0 * KMC;
  const float* pC  = ws + OFF_S2C  + n0 * KMC;
  const float* pXG = ws + OFF_XGAP + n0 * HH;
  const float* pXC = ws + OFF_XCT  + n0 * HH;
  sg[tid] = pG[tid];
  sc[tid] = pC[tid];
  sxg[tid] = pXG[tid]; sxg[tid + 512] = pXG[tid + 512];
  sxc[tid] = pXC[tid]; sxc[tid + 512] = pXC[tid + 512];
  // ---- SpMM: thread (r,k) accumulates T_G and T_C for its row/column ----
  {
    int r = tid >> 4, k = tid & 15;      // 32 rows x 16 cols
    size_t row = n0 + r;
    int nnz = ((const int*)(ws + OFF_ENNZ))[row];
    const unsigned short* eidx = (const unsigned short*)(ws + OFF_EIDX) + row * CAP;
    const float* ewg = ws + OFF_EWG + row * CAP;
    const float* ewc = ws + OFF_EWC + row * CAP;
    const float* S2G = ws + OFF_S2G + (size_t)b * NNODE * KMC;
    const float* S2C = ws + OFF_S2C + (size_t)b * NNODE * KMC;
    float ag = 0.f, ac = 0.f;
    int e = 0;
    for (; e + 1 < nnz; e += 2) {        // 4 independent gathers in flight
      int m0 = eidx[e], m1 = eidx[e + 1];
      float g0 = ewg[e], g1 = ewg[e + 1];
      float c0 = ewc[e], c1 = ewc[e + 1];
      ag += g0 * S2G[(size_t)m0 * KMC + k] + g1 * S2G[(size_t)m1 * KMC + k];
      ac += c0 * S2C[(size_t)m0 * KMC + k] + c1 * S2C[(size_t)m1 * KMC + k];
    }
    if (e < nnz) {
      int m = eidx[e];
      ag += ewg[e] * S2G[(size_t)m * KMC + k];
      ac += ewc[e] * S2C[(size_t)m * KMC + k];
    }
    stg[r * 16 + k] = ag;
    stc[r * 16 + k] = ac;
  }
  __syncthreads();
  // ---- red2: two 256-thread subgroups each reduce 16 rows, atomic commit ----
  int sub = tid >> 8, t = tid & 255;
  { int k0 = t >> 5, h0 = t & 31;
    float og0 = 0.f, og1 = 0.f, oc0 = 0.f, oc1 = 0.f;
#pragma unroll
    for (int i = 0; i < 16; i++) {
      int r = sub * 16 + i;
      float xgv = sxg[r*32 + h0], xcv = sxc[r*32 + h0];
      og0 += sg[r*16 + k0]     * xgv;
      og1 += sg[r*16 + k0 + 8] * xgv;
      oc0 += sc[r*16 + k0]     * xcv;
      oc1 += sc[r*16 + k0 + 8] * xcv;
    }
    atomicAdd(&ws[OFF_OUTG + b*512 + k0*32 + h0],     og0);
    atomicAdd(&ws[OFF_OUTG + b*512 + (k0+8)*32 + h0], og1);
    atomicAdd(&ws[OFF_OUTC + b*512 + k0*32 + h0],     oc0);
    atomicAdd(&ws[OFF_OUTC + b*512 + (k0+8)*32 + h0], oc1);
  }
  { int kk = t >> 4, l = t & 15;
    float gg = 0.f, gc = 0.f, ag = 0.f, ac = 0.f;
#pragma unroll
    for (int i = 0; i < 16; i++) {
      int r = sub * 16 + i;
      float sgk = sg[r*16 + kk], sck = sc[r*16 + kk];
      gg += sgk * sg [r*16 + l];
      gc += sck * sc [r*16 + l];
      ag += sgk * stg[r*16 + l];
      ac += sck * stc[r*16 + l];
    }
    atomicAdd(&ws[OFF_G2G + b*256 + t], gg);
    atomicAdd(&ws[OFF_G2C + b*256 + t], gc);
    atomicAdd(&ws[OFF_OAG + b*256 + t], ag);
    atomicAdd(&ws[OFF_OAC + b*256 + t], ac);
  }
  // ---- per-node loss partials for this 32-node chunk ----
  if (tid < 32) {
    size_t gn = n0 + tid;
    float ng = 0.f, nc = 0.f;
#pragma unroll
    for (int j = 0; j < KMC; j++) {
      float a = sg[tid*16 + j], c2 = sc[tid*16 + j];
      ng += a*a; nc += c2*c2;
    }
    float dgv = ws[OFF_DGAP + gn];
    float dcv = ws[OFF_DCT + gn];
    float d   = ws[OFF_D + gn];
    float2 s  = ((const float2*)(ws + OFF_SRW))[gn];
    float sq  = ws[OFF_SQCT + gn];
    float nmr = ws[OFF_NUMRW + gn];
    float sasv= ws[OFF_SAS + gn];
    float u0 = dgv*ng, u1 = dcv*nc, u2 = ng, u3 = nc;
    float u4 = d*(s.x*s.x + s.y*s.y), u5 = nmr, u6 = d*sq, u7 = sasv;
    float u8 = sq, u9 = s.x*s.x, u10 = s.x*s.y, u11 = s.y*s.y;
#pragma unroll
    for (int off = 16; off >= 1; off >>= 1) {
      u0 += __shfl_xor(u0, off, 32);  u1 += __shfl_xor(u1, off, 32);
      u2 += __shfl_xor(u2, off, 32);  u3 += __shfl_xor(u3, off, 32);
      u4 += __shfl_xor(u4, off, 32);  u5 += __shfl_xor(u5, off, 32);
      u6 += __shfl_xor(u6, off, 32);  u7 += __shfl_xor(u7, off, 32);
      u8 += __shfl_xor(u8, off, 32);  u9 += __shfl_xor(u9, off, 32);
      u10 += __shfl_xor(u10, off, 32); u11 += __shfl_xor(u11, off, 32);
    }
    if (tid == 0) {
      float* bs = ws + OFF_BSUM + b*12;
      atomicAdd(bs + 0, u0);  atomicAdd(bs + 1, u1);  atomicAdd(bs + 2, u2);
      atomicAdd(bs + 3, u3);  atomicAdd(bs + 4, u4);  atomicAdd(bs + 5, u5);
      atomicAdd(bs + 6, u6);  atomicAdd(bs + 7, u7);  atomicAdd(bs + 8, u8);
      atomicAdd(bs + 9, u9);  atomicAdd(bs + 10, u10); atomicAdd(bs + 11, u11);
    }
  }
}

// ============ K4: batch losses (5-way block reduction + BSUM scalars), adj norm,
//              MLP head, log_softmax; loss totals via atomicAdd ============
__global__ __launch_bounds__(256) void k_batch2(
    const float* __restrict__ W2g_rel, const float* __restrict__ b2g, const float* __restrict__ W2g_root,
    const float* __restrict__ Wcat, const float* __restrict__ bcat,
    const float* __restrict__ W2, const float* __restrict__ b2,
    const float* __restrict__ W3, const float* __restrict__ b3,
    float* __restrict__ out, float* __restrict__ ws)
{
  __shared__ float sOAg[256], sOAc[256], sOutg[512], sOutc[512];
  __shared__ float sW2grel[1024], sW2groot[1024], sWcat[2048], sW2l[1024];
  __shared__ float sPg[512], sPc[512], sXg2[512], sXc2[512], sHt[512];
  __shared__ float sHs[32], sH2[32], sLg[16], sScal[2];
  __shared__ float sdkg[16], sdkc[16];
  __shared__ float smm[5][4];
  int b = blockIdx.x, tid = threadIdx.x;
  sOAg[tid] = ws[OFF_OAG + b*256 + tid];
  sOAc[tid] = ws[OFF_OAC + b*256 + tid];
  sOutg[tid]       = ws[OFF_OUTG + b*512 + tid];
  sOutg[tid + 256] = ws[OFF_OUTG + b*512 + tid + 256];
  sOutc[tid]       = ws[OFF_OUTC + b*512 + tid];
  sOutc[tid + 256] = ws[OFF_OUTC + b*512 + tid + 256];
  for (int i = tid; i < 1024; i += 256) { sW2grel[i] = W2g_rel[i]; sW2groot[i] = W2g_root[i]; sW2l[i] = W2[i]; }
  for (int i = tid; i < 2048; i += 256) sWcat[i] = Wcat[i];
  // remaining block reductions: frob2, frobg2, frobc2, num1, num2u
  float v[5];
  v[0] = (tid < 32) ? ws[OFF_FROB + b*32 + tid] : 0.f;
  float gv = ws[OFF_G2G + b*256 + tid];
  float cv = ws[OFF_G2C + b*256 + tid];
  v[1] = gv*gv; v[2] = cv*cv;
  __syncthreads();                      // publish sOAg/sOAc for diag reads
  v[3] = (tid < 16) ? sOAg[tid*17] : 0.f;
  v[4] = (tid < 16) ? sOAc[tid*17] : 0.f;
  blk_sum5(v, smm, tid);
  float frob2 = v[0], frobg2 = v[1], frobc2 = v[2], num1 = v[3], num2u = v[4];
  float vol = ws[OFF_VOL + b];
  float ivol = 1.0f / (vol + EPS15);
  if (tid == 0) {
    const float* bs = ws + OFF_BSUM + b*12;
    float den1 = bs[0], den2u = bs[1], trg = bs[2], trc = bs[3];
    float denrw = bs[4], num = bs[5], sds = bs[6], sas = bs[7], denct = bs[8];
    float g00 = bs[9], g01 = bs[10], g11 = bs[11];
    float mcrw = -num / (denrw + EPS15);
    float ctb  = (sds - sas) / (denct + EPS15);
    float nrw = sqrtf(g00*g00 + 2.f*g01*g01 + g11*g11);
    float olrw = sqrtf(fmaxf(2.f - 2.f*(g00 + g11)/(nrw*1.41421356237f), 0.f));
    float nct = sqrtf(frob2);
    float olct = sqrtf(fmaxf(2.f - 2.f*denct/(nct*5.65685424949f), 0.f));
    float mc1 = -num1 / (den1 + EPS15);
    float mc2 = -(num2u*ivol) / (den2u*ivol + EPS15);
    float ol1 = sqrtf(fmaxf(2.f - 2.f*trg/(sqrtf(frobg2)*4.f), 0.f));
    float ol2 = sqrtf(fmaxf(2.f - 2.f*trc/(sqrtf(frobc2)*4.f), 0.f));
    atomicAdd(out + 160, (mcrw + ctb + mc1 + mc2) * 0.0625f);
    atomicAdd(out + 161, (olrw + olct + ol1 + ol2) * 0.0625f);
  }
  sOAc[tid] *= ivol;
  __syncthreads();
  if (tid < 16) { sOAg[tid*17] = 0.f; sOAc[tid*17] = 0.f; }
  __syncthreads();
  if (tid < 16) {
    float rg = 0.f, rc = 0.f;
#pragma unroll
    for (int l = 0; l < 16; l++) { rg += sOAg[tid*16 + l]; rc += sOAc[tid*16 + l]; }
    sdkg[tid] = sqrtf(rg) + EPS15;
    sdkc[tid] = sqrtf(rc) + EPS15;
  }
  __syncthreads();
  { int k = tid >> 4, l = tid & 15;
    sOAg[tid] /= (sdkg[k]*sdkg[l]);
    sOAc[tid] /= (sdkc[k]*sdkc[l]); }
  __syncthreads();
  { int k = tid >> 5, h = tid & 31;
    float p0 = 0, p1 = 0, q0 = 0, q1 = 0;
#pragma unroll
    for (int l = 0; l < 16; l++) {
      p0 += sOAg[k*16 + l] * sOutg[l*32 + h];
      p1 += sOAg[(k+8)*16 + l] * sOutg[l*32 + h];
      q0 += sOAc[k*16 + l] * sOutc[l*32 + h];
      q1 += sOAc[(k+8)*16 + l] * sOutc[l*32 + h];
    }
    sPg[k*32 + h] = p0; sPg[(k+8)*32 + h] = p1;
    sPc[k*32 + h] = q0; sPc[(k+8)*32 + h] = q1;
  }
  __syncthreads();
  { int k = tid >> 5, h = tid & 31;
    float bb2 = b2g[h];
    float a0 = bb2, a1 = bb2, c0 = bb2, c1 = bb2;
#pragma unroll
    for (int q = 0; q < 32; q++) {
      float wr = sW2grel[q*32 + h], wo = sW2groot[q*32 + h];
      a0 += sPg[k*32 + q]*wr + sOutg[k*32 + q]*wo;
      a1 += sPg[(k+8)*32 + q]*wr + sOutg[(k+8)*32 + q]*wo;
      c0 += sPc[k*32 + q]*wr + sOutc[k*32 + q]*wo;
      c1 += sPc[(k+8)*32 + q]*wr + sOutc[(k+8)*32 + q]*wo;
    }
    sXg2[k*32 + h] = a0; sXg2[(k+8)*32 + h] = a1;
    sXc2[k*32 + h] = c0; sXc2[(k+8)*32 + h] = c1;
  }
  __syncthreads();
  { int k = tid >> 5, h = tid & 31;
    float bb = bcat[h];
    float t0 = bb, t1 = bb;
#pragma unroll
    for (int q = 0; q < 32; q++) {
      float w1v = sWcat[q*32 + h], w2v = sWcat[(q+32)*32 + h];
      t0 += sXg2[k*32 + q]*w1v + sXc2[k*32 + q]*w2v;
      t1 += sXg2[(k+8)*32 + q]*w1v + sXc2[(k+8)*32 + q]*w2v;
    }
    sHt[k*32 + h] = fmaxf(t0, 0.f);
    sHt[(k+8)*32 + h] = fmaxf(t1, 0.f);
  }
  __syncthreads();
  if (tid < 32) {
    float s = 0.f;
#pragma unroll
    for (int k = 0; k < 16; k++) s += sHt[k*32 + tid];
    sHs[tid] = s;
  }
  __syncthreads();
  if (tid < 32) {
    float a = b2[tid];
#pragma unroll
    for (int q = 0; q < 32; q++) a += sHs[q]*sW2l[q*32 + tid];
    sH2[tid] = fmaxf(a, 0.f);
  }
  __syncthreads();
  if (tid < 10) {
    float a = b3[tid];
#pragma unroll
    for (int q = 0; q < 32; q++) a += sH2[q]*W3[q*10 + tid];
    sLg[tid] = a;
  }
  __syncthreads();
  if (tid == 0) {
    float m = sLg[0];
    for (int o = 1; o < 10; o++) m = fmaxf(m, sLg[o]);
    float se = 0.f;
    for (int o = 0; o < 10; o++) se += __expf(sLg[o] - m);
    sScal[0] = m; sScal[1] = logf(se);
  }
  __syncthreads();
  if (tid < 10) out[b*10 + tid] = sLg[tid] - sScal[0] - sScal[1];
}

extern "C" void kernel_launch(void* const* d_in, const int* in_sizes, int n_in,
                              void* d_out, int out_size, void* d_ws, size_t ws_size,
                              hipStream_t stream)
{
  const float* x       = (const float*)d_in[0];
  const float* adj     = (const float*)d_in[1];
  // d_in[2] = mask (all true) — identity, ignored
  const float* W1      = (const float*)d_in[3];
  const float* b1      = (const float*)d_in[4];
  const float* Wrw     = (const float*)d_in[5];
  const float* brw     = (const float*)d_in[6];
  const float* Wg_rel  = (const float*)d_in[7];
  const float* bg      = (const float*)d_in[8];
  const float* Wg_root = (const float*)d_in[9];
  const float* Wmcg    = (const float*)d_in[10];
  const float* bmcg    = (const float*)d_in[11];
  const float* W2g_rel = (const float*)d_in[12];
  const float* b2g     = (const float*)d_in[13];
  const float* W2g_root= (const float*)d_in[14];
  const float* Wct     = (const float*)d_in[15];
  const float* bct     = (const float*)d_in[16];
  const float* Wc_rel  = (const float*)d_in[17];
  const float* bc      = (const float*)d_in[18];
  const float* Wc_root = (const float*)d_in[19];
  const float* Wmcc    = (const float*)d_in[20];
  const float* bmcc    = (const float*)d_in[21];
  const float* Wcat    = (const float*)d_in[22];
  const float* bcat    = (const float*)d_in[23];
  const float* W2      = (const float*)d_in[24];
  const float* b2      = (const float*)d_in[25];
  const float* W3      = (const float*)d_in[26];
  const float* b3      = (const float*)d_in[27];
  float* out = (float*)d_out;
  float* ws  = (float*)d_ws;

  k_fused0<<<dim3(3072), dim3(256), 0, stream>>>(adj, x, W1, b1, Wrw, brw, Wct, bct, ws);
  k_edgefeat<<<dim3(1552), dim3(256), 0, stream>>>(Wg_rel, bg, Wg_root, Wc_rel, bc, Wc_root,
                                                   Wmcg, bmcg, Wmcc, bmcc, out, ws);
  k_passred<<<dim3(512), dim3(512), 0, stream>>>(ws);
  k_batch2<<<dim3(16), dim3(256), 0, stream>>>(W2g_rel, b2g, W2g_root, Wcat, bcat,
                                               W2, b2, W3, b3, out, ws);
}

// Round 6
// 242.386 us; speedup vs baseline: 1.0450x; 1.0450x over previous
//
#include <hip/hip_runtime.h>
#include <math.h>

#define BB   16
#define NNODE 1024
#define INF_ 128
#define HH   32
#define KMC  16
#define CAP  128
#define EPS15 1e-15f

typedef float v4f __attribute__((ext_vector_type(4)));

// ---- workspace layout (float offsets) ----
#define OFF_X      0           // [B*N*32]
#define OFF_SRW    524288      // float2 [B*N]
#define OFF_SQCT   557056      // [B*N]
#define OFF_SCT    573440      // [B*N*32]
#define OFF_D      1097728     // [B*N]
#define OFF_NUMRW  1114112
#define OFF_SAS    1130496
#define OFF_DGAP   1146880
#define OFF_DCT    1163264
#define OFF_XGAP   2228224     // [B*N*32]
#define OFF_XCT    2752512     // [B*N*32]
#define OFF_S2G    3276800     // [B*N*16]
#define OFF_S2C    3538944
#define OFF_FROB   4325376     // [B*32]
#define OFF_VOL    4325888     // [16]
#define OFF_OUTG   4326032     // [B*16*32]
#define OFF_OUTC   4334224
#define OFF_G2G    4342416     // [B*16*16]
#define OFF_G2C    4346512
#define OFF_OAG    4350608
#define OFF_OAC    4354704
// ---- edge cache ----
#define OFF_ENNZ   4358800     // int[16384]
#define OFF_EIDX   4375184     // u16[16384*CAP] = 1048576 floats
#define OFF_EWG    5423760     // float[16384*CAP]
#define OFF_EWC    7520912     // float[16384*CAP]
#define OFF_PACK   9618064     // float4 [B*N] : (srw.x, srw.y, sqct, 0)
#define OFF_BSUM   9683600     // [B*12] per-batch loss partials (atomic, from k_passred)

__device__ __forceinline__ float wave_sum(float v) {
#pragma unroll
  for (int off = 32; off >= 1; off >>= 1) v += __shfl_xor(v, off, 64);
  return v;
}

__device__ __forceinline__ void wave_sum4(float& a, float& b, float& c, float& d) {
#pragma unroll
  for (int off = 32; off >= 1; off >>= 1) {
    a += __shfl_xor(a, off, 64);
    b += __shfl_xor(b, off, 64);
    c += __shfl_xor(c, off, 64);
    d += __shfl_xor(d, off, 64);
  }
}

__device__ __forceinline__ float blk_sum(float v, float* sred, int tid) {
  v = wave_sum(v);
  __syncthreads();
  if ((tid & 63) == 0) sred[tid >> 6] = v;
  __syncthreads();
  return sred[0] + sred[1] + sred[2] + sred[3];
}

// 5 simultaneous block reductions (2 syncthreads total)
__device__ __forceinline__ void blk_sum5(float* v, float (*sm)[4], int tid) {
  int w = tid >> 6, lane = tid & 63;
#pragma unroll
  for (int i = 0; i < 5; i++) {
#pragma unroll
    for (int off = 32; off >= 1; off >>= 1) v[i] += __shfl_xor(v[i], off, 64);
  }
  if (lane == 0) {
#pragma unroll
    for (int i = 0; i < 5; i++) sm[i][w] = v[i];
  }
  __syncthreads();
#pragma unroll
  for (int i = 0; i < 5; i++) v[i] = sm[i][0] + sm[i][1] + sm[i][2] + sm[i][3];
}

// ============ K1: blocks [0,1024) = adj scan->edge list (4 rows/wave, NO barriers —
//              s_e32[w][rr] is wave-private) ; [1024,3072) = prep ============
__global__ __launch_bounds__(256) void k_fused0(
    const float* __restrict__ adj, const float* __restrict__ x,
    const float* __restrict__ W1, const float* __restrict__ b1,
    const float* __restrict__ Wrw, const float* __restrict__ brw,
    const float* __restrict__ Wct, const float* __restrict__ bct,
    float* __restrict__ ws)
{
  __shared__ __align__(16) float sW1[INF_*HH];
  __shared__ __align__(16) float sWct[HH*HH];
  __shared__ float sWrw[HH*2];
  __shared__ float sb1[HH], sbct[HH], sbrw[2];
  __shared__ __align__(16) float sx[8*INF_];
  __shared__ float sX[8*HH];
  __shared__ unsigned int s_e32[4][4][CAP/2];
  int tid = threadIdx.x;
  if (blockIdx.x < 1024) {
    // -------- scan role: 4 rows per wave, 16 NT loads in flight --------
    int w = tid >> 6, lane = tid & 63;
    int row0 = blockIdx.x * 16 + w * 4;
    v4f v[16];
#pragma unroll
    for (int rr = 0; rr < 4; rr++) {
      const v4f* ar = (const v4f*)(adj + (size_t)(row0 + rr) * NNODE);
#pragma unroll
      for (int it = 0; it < 4; it++)
        v[rr*4 + it] = __builtin_nontemporal_load(&ar[it*64 + lane]);
    }
#pragma unroll
    for (int rr = 0; rr < 4; rr++) {
      int row = row0 + rr;
      int c = 0;
#pragma unroll
      for (int it = 0; it < 4; it++) {
        v4f a4 = v[rr*4 + it];
        c += (a4.x != 0.f) + (a4.y != 0.f) + (a4.z != 0.f) + (a4.w != 0.f);
      }
      int p = c;
#pragma unroll
      for (int off = 1; off < 64; off <<= 1) {
        int t = __shfl_up(p, off, 64);
        if (lane >= off) p += t;
      }
      int excl = p - c;
      int total = __shfl(p, 63, 64);
      unsigned short* es = (unsigned short*)s_e32[w][rr];
      int pos = excl;
#pragma unroll
      for (int it = 0; it < 4; it++) {
        v4f a4 = v[rr*4 + it];
        int m0 = it*256 + lane*4;
        if (a4.x != 0.f) { if (pos < CAP) es[pos] = (unsigned short)(m0+0); pos++; }
        if (a4.y != 0.f) { if (pos < CAP) es[pos] = (unsigned short)(m0+1); pos++; }
        if (a4.z != 0.f) { if (pos < CAP) es[pos] = (unsigned short)(m0+2); pos++; }
        if (a4.w != 0.f) { if (pos < CAP) es[pos] = (unsigned short)(m0+3); pos++; }
      }
      int nnzc = total < CAP ? total : CAP;
      // no __syncthreads: s_e32[w][rr] written & read by this wave only (lgkmcnt orders)
      unsigned int* dst = (unsigned int*)((unsigned short*)(ws + OFF_EIDX) + (size_t)row*CAP);
      int n32 = (nnzc + 1) >> 1;
      if (lane < n32) dst[lane] = s_e32[w][rr][lane];
      if (lane == 0) {
        ((int*)(ws + OFF_ENNZ))[row] = nnzc;
        ws[OFF_D + row] = (float)total;
      }
    }
  } else {
    // -------- prep role --------
    for (int i = tid; i < INF_*HH/4; i += 256)
      ((float4*)sW1)[i] = ((const float4*)W1)[i];
    ((float4*)sWct)[tid] = ((const float4*)Wct)[tid];
    if (tid < HH*2) sWrw[tid] = Wrw[tid];
    if (tid < HH) { sb1[tid] = b1[tid]; sbct[tid] = bct[tid]; }
    if (tid < 2) sbrw[tid] = brw[tid];
    size_t row0 = (size_t)(blockIdx.x - 1024) * 8;
    ((float4*)sx)[tid] = ((const float4*)(x + row0 * INF_))[tid];
    __syncthreads();
    int r = tid >> 5, h = tid & 31;
    float acc = sb1[h];
#pragma unroll 8
    for (int k = 0; k < INF_; k++) acc += sx[r*INF_ + k] * sW1[k*HH + h];
    size_t row = row0 + r;
    ws[OFF_X + row*HH + h] = acc;
    sX[r*HH + h] = acc;
    __syncthreads();
    // sct softmax over 32
    float sraw = sbct[h];
#pragma unroll
    for (int k = 0; k < HH; k++) sraw += sX[r*HH + k] * sWct[k*HH + h];
    float mx = sraw;
#pragma unroll
    for (int off = 16; off >= 1; off >>= 1) mx = fmaxf(mx, __shfl_xor(mx, off, 32));
    float e = __expf(sraw - mx);
    float sum = e;
#pragma unroll
    for (int off = 16; off >= 1; off >>= 1) sum += __shfl_xor(sum, off, 32);
    float sv = e / sum;
    ws[OFF_SCT + row*HH + h] = sv;
    float sq = sv * sv;
#pragma unroll
    for (int off = 16; off >= 1; off >>= 1) sq += __shfl_xor(sq, off, 32);
    // srw (k=2)
    float xv = sX[r*HH + h];
    float t0 = xv * sWrw[h*2 + 0];
    float t1 = xv * sWrw[h*2 + 1];
#pragma unroll
    for (int off = 16; off >= 1; off >>= 1) { t0 += __shfl_xor(t0, off, 32); t1 += __shfl_xor(t1, off, 32); }
    if (h == 0) {
      ws[OFF_SQCT + row] = sq;
      float r0 = t0 + sbrw[0], r1 = t1 + sbrw[1];
      float m2 = fmaxf(r0, r1);
      float e0 = __expf(r0 - m2), e1 = __expf(r1 - m2);
      float inv = 1.0f / (e0 + e1);
      float s0 = e0*inv, s1 = e1*inv;
      ((float2*)(ws + OFF_SRW))[row] = make_float2(s0, s1);
      ((float4*)(ws + OFF_PACK))[row] = make_float4(s0, s1, sq, 0.f);
    }
  }
}

// ============ K2 (REVERTED to best measured variant, 41.1 µs):
//              [0,4096) edge weights (4-lane teams) + row stats + y (LDS) +
//              DGC/feat (256-thread) + S2 softmax ; [4096,4608) gramfrob ;
//              [4608,4624) VOL + zero accumulators + BSUM + loss outputs ============
__global__ __launch_bounds__(256) void k_edgefeat(
    const float* __restrict__ Wg_rel, const float* __restrict__ bg, const float* __restrict__ Wg_root,
    const float* __restrict__ Wc_rel, const float* __restrict__ bc, const float* __restrict__ Wc_root,
    const float* __restrict__ Wmcg, const float* __restrict__ bmcg,
    const float* __restrict__ Wmcc, const float* __restrict__ bmcc,
    float* __restrict__ out, float* __restrict__ ws)
{
  __shared__ unsigned short s_m[4][CAP];     // u16: halve LDS
  __shared__ float s_wg[4][CAP];
  __shared__ float s_wc[4][CAP];
  __shared__ float sp[8][32];
  __shared__ float sred[4];
  __shared__ __align__(16) float sWgrel[HH*HH], sWgroot[HH*HH], sWcrel[HH*HH], sWcroot[HH*HH];
  __shared__ float sbg[HH], sbc[HH];
  __shared__ float sYg[4*HH], sYc[4*HH], sXr[4*HH], sxg[4*HH], sxc[4*HH];
  int tid = threadIdx.x;
  if (blockIdx.x < 4096) {
    // XCD swizzle: xcd = blk&7 handles batches {2*xcd, 2*xcd+1}
    int xcd = blockIdx.x & 7;
    int idx = blockIdx.x >> 3;              // 0..511
    int b = xcd*2 + (idx >> 8);             // batch
    int chunk = idx & 255;                  // 0..255
    int base4 = b*NNODE + chunk*4;          // first of this block's 4 rows
    // ---- stage DGC weights (hot in L2; overlaps phase A latency) ----
    ((float4*)sWgrel)[tid]  = ((const float4*)Wg_rel)[tid];
    ((float4*)sWgroot)[tid] = ((const float4*)Wg_root)[tid];
    ((float4*)sWcrel)[tid]  = ((const float4*)Wc_rel)[tid];
    ((float4*)sWcroot)[tid] = ((const float4*)Wc_root)[tid];
    if (tid < HH)  { sbg[tid] = bg[tid]; sbc[tid] = bc[tid]; }
    if (tid < 128) sXr[tid] = ws[OFF_X + (size_t)base4*HH + tid];
    // VOL partial (redundant per-block; avoids cross-kernel dependency for ivol)
    float vp = 0.f;
#pragma unroll
    for (int i = 0; i < 4; i++) vp += ws[OFF_D + (size_t)b*NNODE + tid + i*256];

    const float* X = ws + OFF_X;
    const float2* srw = (const float2*)(ws + OFF_SRW);
    const float* sqct = ws + OFF_SQCT;
    const float* sct = ws + OFF_SCT;
    const float4* pack = (const float4*)(ws + OFF_PACK) + (size_t)b*NNODE;
    int w = tid >> 6, lane = tid & 63;
    int tm = lane & 3;                      // 4-lane team member
    int row = base4 + w;
    int nnz = ((const int*)(ws + OFF_ENNZ))[row];
    const unsigned short* eidx = (const unsigned short*)(ws + OFF_EIDX) + (size_t)row*CAP;
    // own-row fragment: 8 floats per lane (team covers all 32)
    const float4* cn4 = (const float4*)(sct + (size_t)row * HH);
    float4 c0 = cn4[tm*2], c1 = cn4[tm*2 + 1];
    float2 srwn = srw[row];
    float f_n = srwn.x;
    float sq_n = sqct[row];
    float numrw_p = 0.f, sas_p = 0.f, dg_p = 0.f, dc_p = 0.f;
    // phase A: one edge per 4-lane team (16 teams/wave): 64/64 lanes active at nnz>=16
    for (int e = (lane >> 2); e < nnz; e += 16) {
      int m = eidx[e];
      const float4* cm4 = (const float4*)(sct + ((size_t)b*NNODE + m) * HH);
      float4 d0 = cm4[tm*2], d1 = cm4[tm*2 + 1];
      float dot = c0.x*d0.x + c0.y*d0.y + c0.z*d0.z + c0.w*d0.w
                + c1.x*d1.x + c1.y*d1.y + c1.z*d1.z + c1.w*d1.w;
      dot += __shfl_xor(dot, 1, 64);
      dot += __shfl_xor(dot, 2, 64);        // all 4 team lanes now hold full dot
      float4 pk = pack[m];                  // (srw.x, srw.y, sqct)
      numrw_p += srwn.x*pk.x + srwn.y*pk.y;
      float df = f_n - pk.x;
      float wg = 1.0f - df*df;
      float d2 = sq_n + pk.z - 2.0f*dot;
      float wc = sqrtf(fmaxf(d2, 0.0f) + 1e-12f);
      sas_p += dot;
      dg_p += wg;
      dc_p += wc;
      if (tm == 0) {
        s_m[w][e] = (unsigned short)m;
        s_wg[w][e] = wg;
        s_wc[w][e] = wc;
        size_t eo = (size_t)row*CAP + e;
        ws[OFF_EWG + eo] = wg;
        ws[OFF_EWC + eo] = wc;
      }
    }
    wave_sum4(numrw_p, sas_p, dg_p, dc_p);  // 4x duplicated across team -> scale
    if (lane == 0) {
      ws[OFF_NUMRW + row] = numrw_p * 0.25f;
      ws[OFF_SAS + row] = sas_p * 0.25f;
      ws[OFF_DGAP + row] = dg_p * 0.25f;
      ws[OFF_DCT + row] = dc_p * 0.25f;
    }
    // NO barrier: s_m/s_wg/s_wc are wave-local (written & read by same wave)
    // phase C: 4-way edge-parallel weighted feature accumulation (y stays in LDS)
    int eoff = lane >> 4, hp = lane & 15;   // h = 2*hp
    float yg0 = 0.f, yg1 = 0.f, yc0 = 0.f, yc1 = 0.f;
    for (int e = eoff; e < nnz; e += 4) {
      int m = s_m[w][e];
      float wg = s_wg[w][e], wc = s_wc[w][e];
      float2 xv = ((const float2*)(X + ((size_t)b*NNODE + m)*HH))[hp];
      yg0 += wg*xv.x; yg1 += wg*xv.y;
      yc0 += wc*xv.x; yc1 += wc*xv.y;
    }
    yg0 += __shfl_xor(yg0, 16, 64); yg0 += __shfl_xor(yg0, 32, 64);
    yg1 += __shfl_xor(yg1, 16, 64); yg1 += __shfl_xor(yg1, 32, 64);
    yc0 += __shfl_xor(yc0, 16, 64); yc0 += __shfl_xor(yc0, 32, 64);
    yc1 += __shfl_xor(yc1, 16, 64); yc1 += __shfl_xor(yc1, 32, 64);
    if (eoff == 0) {
      sYg[w*HH + 2*hp] = yg0; sYg[w*HH + 2*hp + 1] = yg1;
      sYc[w*HH + 2*hp] = yc0; sYc[w*HH + 2*hp + 1] = yc1;
    }
    // block reduction for VOL; its 2 barriers also publish staging (sXr/weights)
    float vol = blk_sum(vp, sred, tid);
    float ivol = 1.0f / (vol + EPS15);
    // ---- DGC (feat), all 256 threads: k-dim split x2 + 1 shuffle combine ----
    {
      int r = tid >> 6;                 // wave id == row (sYg/sYc wave-local)
      int h = (tid >> 1) & 31;
      int half = tid & 1;
      int kb = half * 16;
      float accg = 0.f, accg2 = 0.f, accc = 0.f, accc2 = 0.f;
#pragma unroll
      for (int kk = 0; kk < 16; kk++) {
        int k = kb + kk;
        float ygv = sYg[r*HH + k], Xv = sXr[r*HH + k], ycv = sYc[r*HH + k];
        accg  += ygv * sWgrel[k*HH + h];
        accg2 += Xv  * sWgroot[k*HH + h];
        accc  += ycv * sWcrel[k*HH + h];
        accc2 += Xv  * sWcroot[k*HH + h];
      }
      accg  += __shfl_xor(accg, 1, 64);
      accg2 += __shfl_xor(accg2, 1, 64);
      accc  += __shfl_xor(accc, 1, 64);
      accc2 += __shfl_xor(accc2, 1, 64);
      if (half == 0) {
        float xgv = sbg[h] + accg + accg2;
        float xcv = sbc[h] + ivol*accc + accc2;
        size_t rw = (size_t)base4 + r;
        ws[OFF_XGAP + rw*HH + h] = xgv;
        ws[OFF_XCT  + rw*HH + h] = xcv;
        sxg[r*HH + h] = xgv;
        sxc[r*HH + h] = xcv;
      }
    }
    __syncthreads();
    // ---- S2 softmaxes (16-wide, G half / C half); weights direct from hot L2 ----
    if (tid < 128) {
      int r = tid >> 5, h = tid & 31;
      int j = h & 15, halfsel = h >> 4;
      const float* sin_ = halfsel ? sxc : sxg;
      const float* sw = halfsel ? Wmcc : Wmcg;
      float raw = halfsel ? bmcc[j] : bmcg[j];
#pragma unroll
      for (int k = 0; k < HH; k++) raw += sin_[r*HH + k] * sw[k*KMC + j];
      float mx = raw;
#pragma unroll
      for (int off = 8; off >= 1; off >>= 1) mx = fmaxf(mx, __shfl_xor(mx, off, 16));
      float e = __expf(raw - mx);
      float sum = e;
#pragma unroll
      for (int off = 8; off >= 1; off >>= 1) sum += __shfl_xor(sum, off, 16);
      float sv = e / sum;
      size_t rw = (size_t)base4 + r;
      if (halfsel == 0) ws[OFF_S2G + rw*KMC + j] = sv;
      else              ws[OFF_S2C + rw*KMC + j] = sv;
    }
  } else if (blockIdx.x < 4608) {
    // -------- gramfrob role (XCD-affine) --------
    int blk = blockIdx.x - 4096;     // 0..511
    int xcd = blk & 7;
    int idx = blk >> 3;              // 0..63
    int b = xcd*2 + (idx >> 5);
    int i = idx & 31;
    const float* sct = ws + OFF_SCT + (size_t)b*NNODE*HH;
    int j = tid & 31, seg = tid >> 5;
    float acc = 0.f;
    for (int n = seg*128; n < seg*128 + 128; n++)
      acc += sct[n*HH + i] * sct[n*HH + j];
    sp[seg][j] = acc;
    __syncthreads();
    if (tid < 32) {
      float g = 0.f;
#pragma unroll
      for (int s = 0; s < 8; s++) g += sp[s][tid];
      float p = g * g;
#pragma unroll
      for (int off = 16; off >= 1; off >>= 1) p += __shfl_xor(p, off, 32);
      if (tid == 0) ws[OFF_FROB + b*32 + i] = p;
    }
  } else {
    // -------- batch-prep role: VOL[b] ; zero K3 accumulators + BSUM + loss outs --------
    int b = blockIdx.x - 4608;       // 0..15
    if (b == 0 && tid < 2) out[160 + tid] = 0.f;
    if (tid < 12) ws[OFF_BSUM + b*12 + tid] = 0.f;
    for (int i = tid; i < 2048; i += 256) ws[OFF_OUTG + b*2048 + i] = 0.f;
    float vp = 0.f;
    for (int n = tid; n < NNODE; n += 256) vp += ws[OFF_D + (size_t)b*NNODE + n];
    float vol = blk_sum(vp, sred, tid);
    if (tid == 0) ws[OFF_VOL + b] = vol;
  }
}

// ============ K3: fused edge-SpMM + red2 + BSUM. XCD-affine (S2/X/EW L2-local).
//              512 blocks x 512 threads; one (row,k) pair per thread: 16 k-lanes
//              of a row read CONTIGUOUS S2 bytes (coalesced), G+C in-thread,
//              2-edge unroll -> 4 gathers in flight, no shuffles. ============
__global__ __launch_bounds__(512) void k_passred(float* __restrict__ ws)
{
  __shared__ float sg[32*16], sc[32*16], stg[32*16], stc[32*16];
  __shared__ float sxg[32*32], sxc[32*32];
  // XCD swizzle mirrors k_edgefeat: xcd = blk&7 -> batches {2*xcd, 2*xcd+1}
  int xcd = blockIdx.x & 7;
  int idx = blockIdx.x >> 3;       // 0..63
  int b = xcd*2 + (idx >> 5);
  int chunk = idx & 31;
  int tid = threadIdx.x;
  size_t n0 = (size_t)b * NNODE + chunk * 32;
  const float* pG  = ws + OFF_S2G  + n0 * KMC;
  const float* pC  = ws + OFF_S2C  + n0 * KMC;
  const float* pXG = ws + OFF_XGAP + n0 * HH;
  const float* pXC = ws + OFF_XCT  + n0 * HH;
  sg[tid] = pG[tid];
  sc[tid] = pC[tid];
  sxg[tid] = pXG[tid]; sxg[tid + 512] = pXG[tid + 512];
  sxc[tid] = pXC[tid]; sxc[tid + 512] = pXC[tid + 512];
  // ---- SpMM: thread (r,k) accumulates T_G and T_C for its row/column ----
  {
    int r = tid >> 4, k = tid & 15;      // 32 rows x 16 cols
    size_t row = n0 + r;
    int nnz = ((const int*)(ws + OFF_ENNZ))[row];
    const unsigned short* eidx = (const unsigned short*)(ws + OFF_EIDX) + row * CAP;
    const float* ewg = ws + OFF_EWG + row * CAP;
    const float* ewc = ws + OFF_EWC + row * CAP;
    const float* S2G = ws + OFF_S2G + (size_t)b * NNODE * KMC;
    const float* S2C = ws + OFF_S2C + (size_t)b * NNODE * KMC;
    float ag = 0.f, ac = 0.f;
    int e = 0;
    for (; e + 1 < nnz; e += 2) {        // 4 independent gathers in flight
      int m0 = eidx[e], m1 = eidx[e + 1];
      float g0 = ewg[e], g1 = ewg[e + 1];
      float c0 = ewc[e], c1 = ewc[e + 1];
      ag += g0 * S2G[(size_t)m0 * KMC + k] + g1 * S2G[(size_t)m1 * KMC + k];
      ac += c0 * S2C[(size_t)m0 * KMC + k] + c1 * S2C[(size_t)m1 * KMC + k];
    }
    if (e < nnz) {
      int m = eidx[e];
      ag += ewg[e] * S2G[(size_t)m * KMC + k];
      ac += ewc[e] * S2C[(size_t)m * KMC + k];
    }
    stg[r * 16 + k] = ag;
    stc[r * 16 + k] = ac;
  }
  __syncthreads();
  // ---- red2: two 256-thread subgroups each reduce 16 rows, atomic commit ----
  int sub = tid >> 8, t = tid & 255;
  { int k0 = t >> 5, h0 = t & 31;
    float og0 = 0.f, og1 = 0.f, oc0 = 0.f, oc1 = 0.f;
#pragma unroll
    for (int i = 0; i < 16; i++) {
      int r = sub * 16 + i;
      float xgv = sxg[r*32 + h0], xcv = sxc[r*32 + h0];
      og0 += sg[r*16 + k0]     * xgv;
      og1 += sg[r*16 + k0 + 8] * xgv;
      oc0 += sc[r*16 + k0]     * xcv;
      oc1 += sc[r*16 + k0 + 8] * xcv;
    }
    atomicAdd(&ws[OFF_OUTG + b*512 + k0*32 + h0],     og0);
    atomicAdd(&ws[OFF_OUTG + b*512 + (k0+8)*32 + h0], og1);
    atomicAdd(&ws[OFF_OUTC + b*512 + k0*32 + h0],     oc0);
    atomicAdd(&ws[OFF_OUTC + b*512 + (k0+8)*32 + h0], oc1);
  }
  { int kk = t >> 4, l = t & 15;
    float gg = 0.f, gc = 0.f, ag = 0.f, ac = 0.f;
#pragma unroll
    for (int i = 0; i < 16; i++) {
      int r = sub * 16 + i;
      float sgk = sg[r*16 + kk], sck = sc[r*16 + kk];
      gg += sgk * sg [r*16 + l];
      gc += sck * sc [r*16 + l];
      ag += sgk * stg[r*16 + l];
      ac += sck * stc[r*16 + l];
    }
    atomicAdd(&ws[OFF_G2G + b*256 + t], gg);
    atomicAdd(&ws[OFF_G2C + b*256 + t], gc);
    atomicAdd(&ws[OFF_OAG + b*256 + t], ag);
    atomicAdd(&ws[OFF_OAC + b*256 + t], ac);
  }
  // ---- per-node loss partials for this 32-node chunk ----
  if (tid < 32) {
    size_t gn = n0 + tid;
    float ng = 0.f, nc = 0.f;
#pragma unroll
    for (int j = 0; j < KMC; j++) {
      float a = sg[tid*16 + j], c2 = sc[tid*16 + j];
      ng += a*a; nc += c2*c2;
    }
    float dgv = ws[OFF_DGAP + gn];
    float dcv = ws[OFF_DCT + gn];
    float d   = ws[OFF_D + gn];
    float2 s  = ((const float2*)(ws + OFF_SRW))[gn];
    float sq  = ws[OFF_SQCT + gn];
    float nmr = ws[OFF_NUMRW + gn];
    float sasv= ws[OFF_SAS + gn];
    float u0 = dgv*ng, u1 = dcv*nc, u2 = ng, u3 = nc;
    float u4 = d*(s.x*s.x + s.y*s.y), u5 = nmr, u6 = d*sq, u7 = sasv;
    float u8 = sq, u9 = s.x*s.x, u10 = s.x*s.y, u11 = s.y*s.y;
#pragma unroll
    for (int off = 16; off >= 1; off >>= 1) {
      u0 += __shfl_xor(u0, off, 32);  u1 += __shfl_xor(u1, off, 32);
      u2 += __shfl_xor(u2, off, 32);  u3 += __shfl_xor(u3, off, 32);
      u4 += __shfl_xor(u4, off, 32);  u5 += __shfl_xor(u5, off, 32);
      u6 += __shfl_xor(u6, off, 32);  u7 += __shfl_xor(u7, off, 32);
      u8 += __shfl_xor(u8, off, 32);  u9 += __shfl_xor(u9, off, 32);
      u10 += __shfl_xor(u10, off, 32); u11 += __shfl_xor(u11, off, 32);
    }
    if (tid == 0) {
      float* bs = ws + OFF_BSUM + b*12;
      atomicAdd(bs + 0, u0);  atomicAdd(bs + 1, u1);  atomicAdd(bs + 2, u2);
      atomicAdd(bs + 3, u3);  atomicAdd(bs + 4, u4);  atomicAdd(bs + 5, u5);
      atomicAdd(bs + 6, u6);  atomicAdd(bs + 7, u7);  atomicAdd(bs + 8, u8);
      atomicAdd(bs + 9, u9);  atomicAdd(bs + 10, u10); atomicAdd(bs + 11, u11);
    }
  }
}

// ============ K4: batch losses (5-way block reduction + BSUM scalars), adj norm,
//              MLP head, log_softmax; loss totals via atomicAdd ============
__global__ __launch_bounds__(256) void k_batch2(
    const float* __restrict__ W2g_rel, const float* __restrict__ b2g, const float* __restrict__ W2g_root,
    const float* __restrict__ Wcat, const float* __restrict__ bcat,
    const float* __restrict__ W2, const float* __restrict__ b2,
    const float* __restrict__ W3, const float* __restrict__ b3,
    float* __restrict__ out, float* __restrict__ ws)
{
  __shared__ float sOAg[256], sOAc[256], sOutg[512], sOutc[512];
  __shared__ float sW2grel[1024], sW2groot[1024], sWcat[2048], sW2l[1024];
  __shared__ float sPg[512], sPc[512], sXg2[512], sXc2[512], sHt[512];
  __shared__ float sHs[32], sH2[32], sLg[16], sScal[2];
  __shared__ float sdkg[16], sdkc[16];
  __shared__ float smm[5][4];
  int b = blockIdx.x, tid = threadIdx.x;
  sOAg[tid] = ws[OFF_OAG + b*256 + tid];
  sOAc[tid] = ws[OFF_OAC + b*256 + tid];
  sOutg[tid]       = ws[OFF_OUTG + b*512 + tid];
  sOutg[tid + 256] = ws[OFF_OUTG + b*512 + tid + 256];
  sOutc[tid]       = ws[OFF_OUTC + b*512 + tid];
  sOutc[tid + 256] = ws[OFF_OUTC + b*512 + tid + 256];
  for (int i = tid; i < 1024; i += 256) { sW2grel[i] = W2g_rel[i]; sW2groot[i] = W2g_root[i]; sW2l[i] = W2[i]; }
  for (int i = tid; i < 2048; i += 256) sWcat[i] = Wcat[i];
  // remaining block reductions: frob2, frobg2, frobc2, num1, num2u
  float v[5];
  v[0] = (tid < 32) ? ws[OFF_FROB + b*32 + tid] : 0.f;
  float gv = ws[OFF_G2G + b*256 + tid];
  float cv = ws[OFF_G2C + b*256 + tid];
  v[1] = gv*gv; v[2] = cv*cv;
  __syncthreads();                      // publish sOAg/sOAc for diag reads
  v[3] = (tid < 16) ? sOAg[tid*17] : 0.f;
  v[4] = (tid < 16) ? sOAc[tid*17] : 0.f;
  blk_sum5(v, smm, tid);
  float frob2 = v[0], frobg2 = v[1], frobc2 = v[2], num1 = v[3], num2u = v[4];
  float vol = ws[OFF_VOL + b];
  float ivol = 1.0f / (vol + EPS15);
  if (tid == 0) {
    const float* bs = ws + OFF_BSUM + b*12;
    float den1 = bs[0], den2u = bs[1], trg = bs[2], trc = bs[3];
    float denrw = bs[4], num = bs[5], sds = bs[6], sas = bs[7], denct = bs[8];
    float g00 = bs[9], g01 = bs[10], g11 = bs[11];
    float mcrw = -num / (denrw + EPS15);
    float ctb  = (sds - sas) / (denct + EPS15);
    float nrw = sqrtf(g00*g00 + 2.f*g01*g01 + g11*g11);
    float olrw = sqrtf(fmaxf(2.f - 2.f*(g00 + g11)/(nrw*1.41421356237f), 0.f));
    float nct = sqrtf(frob2);
    float olct = sqrtf(fmaxf(2.f - 2.f*denct/(nct*5.65685424949f), 0.f));
    float mc1 = -num1 / (den1 + EPS15);
    float mc2 = -(num2u*ivol) / (den2u*ivol + EPS15);
    float ol1 = sqrtf(fmaxf(2.f - 2.f*trg/(sqrtf(frobg2)*4.f), 0.f));
    float ol2 = sqrtf(fmaxf(2.f - 2.f*trc/(sqrtf(frobc2)*4.f), 0.f));
    atomicAdd(out + 160, (mcrw + ctb + mc1 + mc2) * 0.0625f);
    atomicAdd(out + 161, (olrw + olct + ol1 + ol2) * 0.0625f);
  }
  sOAc[tid] *= ivol;
  __syncthreads();
  if (tid < 16) { sOAg[tid*17] = 0.f; sOAc[tid*17] = 0.f; }
  __syncthreads();
  if (tid < 16) {
    float rg = 0.f, rc = 0.f;
#pragma unroll
    for (int l = 0; l < 16; l++) { rg += sOAg[tid*16 + l]; rc += sOAc[tid*16 + l]; }
    sdkg[tid] = sqrtf(rg) + EPS15;
    sdkc[tid] = sqrtf(rc) + EPS15;
  }
  __syncthreads();
  { int k = tid >> 4, l = tid & 15;
    sOAg[tid] /= (sdkg[k]*sdkg[l]);
    sOAc[tid] /= (sdkc[k]*sdkc[l]); }
  __syncthreads();
  { int k = tid >> 5, h = tid & 31;
    float p0 = 0, p1 = 0, q0 = 0, q1 = 0;
#pragma unroll
    for (int l = 0; l < 16; l++) {
      p0 += sOAg[k*16 + l] * sOutg[l*32 + h];
      p1 += sOAg[(k+8)*16 + l] * sOutg[l*32 + h];
      q0 += sOAc[k*16 + l] * sOutc[l*32 + h];
      q1 += sOAc[(k+8)*16 + l] * sOutc[l*32 + h];
    }
    sPg[k*32 + h] = p0; sPg[(k+8)*32 + h] = p1;
    sPc[k*32 + h] = q0; sPc[(k+8)*32 + h] = q1;
  }
  __syncthreads();
  { int k = tid >> 5, h = tid & 31;
    float bb2 = b2g[h];
    float a0 = bb2, a1 = bb2, c0 = bb2, c1 = bb2;
#pragma unroll
    for (int q = 0; q < 32; q++) {
      float wr = sW2grel[q*32 + h], wo = sW2groot[q*32 + h];
      a0 += sPg[k*32 + q]*wr + sOutg[k*32 + q]*wo;
      a1 += sPg[(k+8)*32 + q]*wr + sOutg[(k+8)*32 + q]*wo;
      c0 += sPc[k*32 + q]*wr + sOutc[k*32 + q]*wo;
      c1 += sPc[(k+8)*32 + q]*wr + sOutc[(k+8)*32 + q]*wo;
    }
    sXg2[k*32 + h] = a0; sXg2[(k+8)*32 + h] = a1;
    sXc2[k*32 + h] = c0; sXc2[(k+8)*32 + h] = c1;
  }
  __syncthreads();
  { int k = tid >> 5, h = tid & 31;
    float bb = bcat[h];
    float t0 = bb, t1 = bb;
#pragma unroll
    for (int q = 0; q < 32; q++) {
      float w1v = sWcat[q*32 + h], w2v = sWcat[(q+32)*32 + h];
      t0 += sXg2[k*32 + q]*w1v + sXc2[k*32 + q]*w2v;
      t1 += sXg2[(k+8)*32 + q]*w1v + sXc2[(k+8)*32 + q]*w2v;
    }
    sHt[k*32 + h] = fmaxf(t0, 0.f);
    sHt[(k+8)*32 + h] = fmaxf(t1, 0.f);
  }
  __syncthreads();
  if (tid < 32) {
    float s = 0.f;
#pragma unroll
    for (int k = 0; k < 16; k++) s += sHt[k*32 + tid];
    sHs[tid] = s;
  }
  __syncthreads();
  if (tid < 32) {
    float a = b2[tid];
#pragma unroll
    for (int q = 0; q < 32; q++) a += sHs[q]*sW2l[q*32 + tid];
    sH2[tid] = fmaxf(a, 0.f);
  }
  __syncthreads();
  if (tid < 10) {
    float a = b3[tid];
#pragma unroll
    for (int q = 0; q < 32; q++) a += sH2[q]*W3[q*10 + tid];
    sLg[tid] = a;
  }
  __syncthreads();
  if (tid == 0) {
    float m = sLg[0];
    for (int o = 1; o < 10; o++) m = fmaxf(m, sLg[o]);
    float se = 0.f;
    for (int o = 0; o < 10; o++) se += __expf(sLg[o] - m);
    sScal[0] = m; sScal[1] = logf(se);
  }
  __syncthreads();
  if (tid < 10) out[b*10 + tid] = sLg[tid] - sScal[0] - sScal[1];
}

extern "C" void kernel_launch(void* const* d_in, const int* in_sizes, int n_in,
                              void* d_out, int out_size, void* d_ws, size_t ws_size,
                              hipStream_t stream)
{
  const float* x       = (const float*)d_in[0];
  const float* adj     = (const float*)d_in[1];
  // d_in[2] = mask (all true) — identity, ignored
  const float* W1      = (const float*)d_in[3];
  const float* b1      = (const float*)d_in[4];
  const float* Wrw     = (const float*)d_in[5];
  const float* brw     = (const float*)d_in[6];
  const float* Wg_rel  = (const float*)d_in[7];
  const float* bg      = (const float*)d_in[8];
  const float* Wg_root = (const float*)d_in[9];
  const float* Wmcg    = (const float*)d_in[10];
  const float* bmcg    = (const float*)d_in[11];
  const float* W2g_rel = (const float*)d_in[12];
  const float* b2g     = (const float*)d_in[13];
  const float* W2g_root= (const float*)d_in[14];
  const float* Wct     = (const float*)d_in[15];
  const float* bct     = (const float*)d_in[16];
  const float* Wc_rel  = (const float*)d_in[17];
  const float* bc      = (const float*)d_in[18];
  const float* Wc_root = (const float*)d_in[19];
  const float* Wmcc    = (const float*)d_in[20];
  const float* bmcc    = (const float*)d_in[21];
  const float* Wcat    = (const float*)d_in[22];
  const float* bcat    = (const float*)d_in[23];
  const float* W2      = (const float*)d_in[24];
  const float* b2      = (const float*)d_in[25];
  const float* W3      = (const float*)d_in[26];
  const float* b3      = (const float*)d_in[27];
  float* out = (float*)d_out;
  float* ws  = (float*)d_ws;

  k_fused0<<<dim3(3072), dim3(256), 0, stream>>>(adj, x, W1, b1, Wrw, brw, Wct, bct, ws);
  k_edgefeat<<<dim3(4624), dim3(256), 0, stream>>>(Wg_rel, bg, Wg_root, Wc_rel, bc, Wc_root,
                                                   Wmcg, bmcg, Wmcc, bmcc, out, ws);
  k_passred<<<dim3(512), dim3(512), 0, stream>>>(ws);
  k_batch2<<<dim3(16), dim3(256), 0, stream>>>(W2g_rel, b2g, W2g_root, Wcat, bcat,
                                               W2, b2, W3, b3, out, ws);
}